// Round 7
// baseline (516.778 us; speedup 1.0000x reference)
//
#include <hip/hip_runtime.h>
#include <math.h>
#include <cstddef>

// Problem constants
#define BB   16
#define HH   256
#define WW   256
#define CC   64      // channels (= attention token count)
#define NTOK 16      // pooled tokens per (b,c)
#define NDIM 16      // DIM

// ws layout:
//   part : [B][16 tok][16 rc][64 c] fp32  = 262144 floats (1 MiB)
//   frag : [B][8 slot][64 lane][8 j] bf16 =  65536 ushorts (128 KiB)
//     per-batch: 8*64*8 = 4096 ushorts = 512 fragments of 16 B.
//     slot = tcol*2 + kstep
//     element: W[t = tcol*16 + (lane&15)][c = kstep*32 + (lane>>4)*8 + j]
//     i.e. the exact mfma_f32_16x16x32_bf16 B-fragment layout.
//   SINGLE bf16 (no hi/lo split): attn ~= 1/64 uniform (dots ~ +-2.4e-4
//   because pooled tokens are means of 4096 samples), out in +-0.8;
//   single-RNE-bf16 error max ~1e-3 << 8.7e-3 budget. (verified r6: absmax
//   unchanged at the 1.95e-3 harness ref-quantization floor)
#define PART_FLOATS (BB * NTOK * 16 * CC)
#define FRAG_USHORT_PER_B (8 * 64 * 8)   // 4096

typedef short s16x8 __attribute__((ext_vector_type(8)));   // 8 bf16 (4 VGPRs)
typedef float f32x4 __attribute__((ext_vector_type(4)));

// bf16 RNE helper (scalar, used in stage 2 only)
__device__ __forceinline__ unsigned short f2bf_rne(float f) {
    unsigned int u = __float_as_uint(f);
    return (unsigned short)((u + 0x7fffu + ((u >> 16) & 1u)) >> 16);
}

// ---------------------------------------------------------------------------
// Stage 1: partial pooling sums. (unchanged — near coalesced floor)
// ---------------------------------------------------------------------------
__global__ __launch_bounds__(256) void pool_partial(const float* __restrict__ x,
                                                    float* __restrict__ part) {
    const int blk = blockIdx.x;       // b*256 + n*16 + rc
    const int rc  = blk & 15;
    const int n   = (blk >> 4) & 15;
    const int b   = blk >> 8;
    const int ph  = n >> 2, pw = n & 3;
    const int t   = threadIdx.x;
    const int c4  = (t & 15) << 2;
    const int sub = t >> 4;           // 0..15

    const int h0 = ph * 64 + rc * 4;
    const int w0 = pw * 64;
    const float* xb = x + (((size_t)b * HH + h0) * WW + w0) * CC;

    float4 s = make_float4(0.f, 0.f, 0.f, 0.f);
#pragma unroll
    for (int k = 0; k < 16; ++k) {
        const int pos = sub + (k << 4);       // 0..255
        const int row = pos >> 6;
        const int col = pos & 63;
        const float4 v = *(const float4*)(xb + ((size_t)row * WW + col) * CC + c4);
        s.x += v.x; s.y += v.y; s.z += v.z; s.w += v.w;
    }

    __shared__ float lds[16 * 64];
    lds[sub * 64 + c4 + 0] = s.x;
    lds[sub * 64 + c4 + 1] = s.y;
    lds[sub * 64 + c4 + 2] = s.z;
    lds[sub * 64 + c4 + 3] = s.w;
    __syncthreads();

    if (t < 64) {
        float acc = 0.f;
#pragma unroll
        for (int ss = 0; ss < 16; ++ss) acc += lds[ss * 64 + t];
        part[(((size_t)b * NTOK + n) * 16 + rc) * CC + t] = acc;
    }
}

// ---------------------------------------------------------------------------
// Stage 2: tokens -> qk -> dots -> softmax -> bf16 B-fragments (RNE).
// grid = 16 (one per batch).
// ---------------------------------------------------------------------------
__global__ __launch_bounds__(256) void attn_kernel(const float* __restrict__ part,
                                                   const float* __restrict__ w_qkv, // [32][16]
                                                   unsigned short* __restrict__ fragw) {
    const int b = blockIdx.x;
    const int t = threadIdx.x;

    __shared__ float tok[CC * NDIM];   // [c][n]
    __shared__ float ql [CC * NDIM];   // [c][n]
    __shared__ float kl [CC * NDIM];   // [c][n]
    __shared__ float dl [CC * CC];     // [i][j]
    __shared__ float rs [CC];          // 1/rowsum

    const float* pb = part + (size_t)b * NTOK * 16 * CC;

    // tokens[c][n] = mean over patch = (sum of 16 rc-partials)/4096
    for (int idx = t; idx < CC * NDIM; idx += 256) {
        const int c = idx >> 4, n = idx & 15;
        float a = 0.f;
#pragma unroll
        for (int rc = 0; rc < 16; ++rc) a += pb[((size_t)n * 16 + rc) * CC + c];
        tok[c * NDIM + n] = a * (1.0f / 4096.0f);
    }
    __syncthreads();

    // qk[c][d] = sum_n tok[c][n] * w[d][n];  split into q (d<16) and k
    for (int idx = t; idx < CC * 32; idx += 256) {
        const int c = idx >> 5, d = idx & 31;
        float a = 0.f;
#pragma unroll
        for (int n = 0; n < NDIM; ++n) a += tok[c * NDIM + n] * w_qkv[d * NDIM + n];
        if (d < 16) ql[c * NDIM + d] = a;
        else        kl[c * NDIM + (d - 16)] = a;
    }
    __syncthreads();

    // dots[i][j] = 0.25 * sum_n q[i][n]*k[j][n]
    for (int idx = t; idx < CC * CC; idx += 256) {
        const int i = idx >> 6, j = idx & 63;
        float a = 0.f;
#pragma unroll
        for (int n = 0; n < NDIM; ++n) a += ql[i * NDIM + n] * kl[j * NDIM + n];
        dl[idx] = a * 0.25f;
    }
    __syncthreads();

    // row softmax (64 rows, one thread each — tiny)
    if (t < CC) {
        float m = -1e30f;
        for (int j = 0; j < CC; ++j) m = fmaxf(m, dl[t * CC + j]);
        float ssum = 0.f;
        for (int j = 0; j < CC; ++j) {
            const float e = expf(dl[t * CC + j] - m);
            dl[t * CC + j] = e;
            ssum += e;
        }
        rs[t] = 1.0f / ssum;
    }
    __syncthreads();

    // Emit attn[t][c] = dl[t][c]*rs[t] as single-bf16 MFMA B-fragments.
    for (int idx = t; idx < 512; idx += 256) {
        const int tt   = idx >> 3;          // 0..63
        const int oct  = idx & 7;           // c octet
        const int ks   = oct >> 2;          // kstep = c>>5
        const int g    = oct & 3;           // lane>>4 group
        const int slot = (tt >> 4) * 2 + ks;         // 0..7
        const int lanei = (tt & 15) + g * 16;
        const float rr = rs[tt];
        s16x8 hi;
#pragma unroll
        for (int j = 0; j < 8; ++j)
            hi[j] = (short)f2bf_rne(dl[tt * CC + oct * 8 + j] * rr);
        s16x8* dst = (s16x8*)fragw + ((size_t)b * 8 + slot) * 64;
        dst[lanei] = hi;
    }
}

// ---------------------------------------------------------------------------
// Stage 3 (v8): single-bf16 MFMA GEMM, B-in-VGPR, depth-2 x pipeline.
// out[p][t] = gelu(sum_c x[p][c]*attn[t][c])
// v8 vs v7 (neutral total; ablation proved stage is memory-LATENCY-bound,
// not issue-bound — removing 64 MFMA + split VALU moved nothing):
//  - NO LDS, NO __syncthreads: each lane loads its own 8 B-fragments
//    (8 x 16 B, same 8 KB read by all 256 blocks of a batch -> L2-hot)
//    straight into 32 VGPRs. Kills the global->LDS staging + barrier
//    bubble at the head of all 4096 blocks and the 8 ds_read/rb.
//  - depth-2 register double-buffer on x: issue rb0 + frags + rb1 at
//    block start (16 VMEM in flight), prefetch rb+2 during rb compute.
//    Load order (x0, frags, x1) lets counted vmcnt release pack8(rb0)
//    while frags/rb1 are still outstanding.
// A-frag: lane l -> row l&15, k (l>>4)*8+j (m92-m97 refchecked);
// C/D: col=lane&15, row=(lane>>4)*4+reg (m89-verified, r4-r6 passing).
// ---------------------------------------------------------------------------
__device__ __forceinline__ float gelu_fast(float v) {
    // gelu ~= v * sigmoid(1.59576912v + 0.07135482v^3); |err|<2e-4 for |v|<~1.
    const float u = v * v;
    const float z = v * fmaf(0.07135482f, u, 1.59576912f);
    const float e = exp2f(z * -1.44269504f);            // e^{-z}
    return v * __builtin_amdgcn_rcpf(e + 1.0f);
}

// pack 8 fp32 -> 8 bf16 (RNE) via v_cvt_pk_bf16_f32 (1 instr per 2 elems)
__device__ __forceinline__ s16x8 pack8(const float4 a, const float4 b) {
    union { unsigned int u[4]; s16x8 v; } r;
    asm("v_cvt_pk_bf16_f32 %0, %1, %2" : "=v"(r.u[0]) : "v"(a.x), "v"(a.y));
    asm("v_cvt_pk_bf16_f32 %0, %1, %2" : "=v"(r.u[1]) : "v"(a.z), "v"(a.w));
    asm("v_cvt_pk_bf16_f32 %0, %1, %2" : "=v"(r.u[2]) : "v"(b.x), "v"(b.y));
    asm("v_cvt_pk_bf16_f32 %0, %1, %2" : "=v"(r.u[3]) : "v"(b.z), "v"(b.w));
    return r.v;
}

__global__ __launch_bounds__(256) void out_mfma(const float* __restrict__ x,
                                                const unsigned short* __restrict__ frag,
                                                float* __restrict__ out) {
    const int tid  = threadIdx.x;
    const int lane = tid & 63;
    const int wv   = tid >> 6;
    const int blk  = blockIdx.x;          // 4096 blocks, 256 pixels each
    const int b    = blk >> 8;            // 256 blocks per batch
    const int row  = lane & 15;
    const int g    = lane >> 4;

    const size_t pix0 = (size_t)blk * 256 + wv * 64;
    const float* xb = x + (pix0 + row) * CC + g * 8;

    // ---- issue x rowblock 0 ----
    float4 a0 = *(const float4*)(xb);
    float4 a1 = *(const float4*)(xb + 4);
    float4 a2 = *(const float4*)(xb + 32);
    float4 a3 = *(const float4*)(xb + 36);

    // ---- issue the 8 per-lane B-fragments (L2-hot, 16 B each) ----
    const s16x8* fb = (const s16x8*)(frag + (size_t)b * FRAG_USHORT_PER_B);
    s16x8 bf[8];
#pragma unroll
    for (int s = 0; s < 8; ++s) bf[s] = fb[s * 64 + lane];

    // ---- issue x rowblock 1 ----
    const float* x1 = xb + 16 * CC;
    float4 b0 = *(const float4*)(x1);
    float4 b1 = *(const float4*)(x1 + 4);
    float4 b2 = *(const float4*)(x1 + 32);
    float4 b3 = *(const float4*)(x1 + 36);

    float* ob = out + (pix0 + (g << 2)) * CC + row;   // row = lane&15 = t-in-tile

#define TCOLS(RB, AH0, AH1)                                                     \
    _Pragma("unroll")                                                           \
    for (int tcol = 0; tcol < 4; ++tcol) {                                      \
        f32x4 acc = {0.f, 0.f, 0.f, 0.f};                                       \
        acc = __builtin_amdgcn_mfma_f32_16x16x32_bf16(AH0, bf[tcol * 2], acc, 0, 0, 0);     \
        acc = __builtin_amdgcn_mfma_f32_16x16x32_bf16(AH1, bf[tcol * 2 + 1], acc, 0, 0, 0); \
        float* o = ob + (size_t)(RB) * 16 * CC + tcol * 16;                     \
        _Pragma("unroll")                                                       \
        for (int r = 0; r < 4; ++r) o[(size_t)r * CC] = gelu_fast(acc[r]);      \
    }

    // rb0: compute from A-buf, prefetch rb2 into A-buf
    {
        const s16x8 ah0 = pack8(a0, a1);
        const s16x8 ah1 = pack8(a2, a3);
        const float* nx = xb + 32 * CC;
        a0 = *(const float4*)(nx);
        a1 = *(const float4*)(nx + 4);
        a2 = *(const float4*)(nx + 32);
        a3 = *(const float4*)(nx + 36);
        TCOLS(0, ah0, ah1)
    }
    // rb1: compute from B-buf, prefetch rb3 into B-buf
    {
        const s16x8 ah0 = pack8(b0, b1);
        const s16x8 ah1 = pack8(b2, b3);
        const float* nx = xb + 48 * CC;
        b0 = *(const float4*)(nx);
        b1 = *(const float4*)(nx + 4);
        b2 = *(const float4*)(nx + 32);
        b3 = *(const float4*)(nx + 36);
        TCOLS(1, ah0, ah1)
    }
    // rb2: compute from A-buf
    {
        const s16x8 ah0 = pack8(a0, a1);
        const s16x8 ah1 = pack8(a2, a3);
        TCOLS(2, ah0, ah1)
    }
    // rb3: compute from B-buf
    {
        const s16x8 ah0 = pack8(b0, b1);
        const s16x8 ah1 = pack8(b2, b3);
        TCOLS(3, ah0, ah1)
    }
#undef TCOLS
}

// ---------------------------------------------------------------------------
extern "C" void kernel_launch(void* const* d_in, const int* in_sizes, int n_in,
                              void* d_out, int out_size, void* d_ws, size_t ws_size,
                              hipStream_t stream) {
    const float* x     = (const float*)d_in[0];   // (16,256,256,64) fp32
    const float* w_qkv = (const float*)d_in[1];   // (32,16) fp32
    float* out   = (float*)d_out;                 // (16,256,256,64) fp32
    float* part  = (float*)d_ws;                  // 1 MiB
    unsigned short* frag = (unsigned short*)(part + PART_FLOATS); // 128 KiB

    pool_partial<<<BB * NTOK * 16, 256, 0, stream>>>(x, part);
    attn_kernel<<<BB, 256, 0, stream>>>(part, w_qkv, frag);
    out_mfma<<<BB * 256, 256, 0, stream>>>(x, frag, out);
}

// Round 8
// 515.063 us; speedup vs baseline: 1.0033x; 1.0033x over previous
//
#include <hip/hip_runtime.h>
#include <math.h>
#include <cstddef>

// Problem constants
#define BB   16
#define HH   256
#define WW   256
#define CC   64      // channels (= attention token count)
#define NTOK 16      // pooled tokens per (b,c)
#define NDIM 16      // DIM
#define HALF_B 8     // batches per pipelined chunk

// ws layout:
//   part : [B][16 tok][16 rc][64 c] fp32  = 262144 floats (1 MiB)
//   frag : [B][8 slot][64 lane][8 j] bf16 =  65536 ushorts (128 KiB)
//     per-batch: 8*64*8 = 4096 ushorts = 512 fragments of 16 B.
//     slot = tcol*2 + kstep
//     element: W[t = tcol*16 + (lane&15)][c = kstep*32 + (lane>>4)*8 + j]
//     i.e. the exact mfma_f32_16x16x32_bf16 B-fragment layout.
//   SINGLE bf16: attn ~= 1/64 uniform (dots ~ +-2.4e-4), out in +-0.8;
//   single-RNE-bf16 error max ~1e-3 << 8.7e-3 budget (verified r6/r7).
#define PART_FLOATS (BB * NTOK * 16 * CC)
#define FRAG_USHORT_PER_B (8 * 64 * 8)   // 4096

typedef short s16x8 __attribute__((ext_vector_type(8)));   // 8 bf16 (4 VGPRs)
typedef float f32x4 __attribute__((ext_vector_type(4)));

// bf16 RNE helper (scalar, used in stage 2 only)
__device__ __forceinline__ unsigned short f2bf_rne(float f) {
    unsigned int u = __float_as_uint(f);
    return (unsigned short)((u + 0x7fffu + ((u >> 16) & 1u)) >> 16);
}

// ---------------------------------------------------------------------------
// Stage 1: partial pooling sums, batch-offset version (b0 = first batch).
// grid = HALF_B*256 blocks. Unchanged math, near coalesced-read floor.
// ---------------------------------------------------------------------------
__global__ __launch_bounds__(256) void pool_partial(const float* __restrict__ x,
                                                    float* __restrict__ part,
                                                    int b0) {
    const int blk = blockIdx.x;       // (b-b0)*256 + n*16 + rc
    const int rc  = blk & 15;
    const int n   = (blk >> 4) & 15;
    const int b   = b0 + (blk >> 8);
    const int ph  = n >> 2, pw = n & 3;
    const int t   = threadIdx.x;
    const int c4  = (t & 15) << 2;
    const int sub = t >> 4;           // 0..15

    const int h0 = ph * 64 + rc * 4;
    const int w0 = pw * 64;
    const float* xb = x + (((size_t)b * HH + h0) * WW + w0) * CC;

    float4 s = make_float4(0.f, 0.f, 0.f, 0.f);
#pragma unroll
    for (int k = 0; k < 16; ++k) {
        const int pos = sub + (k << 4);       // 0..255
        const int row = pos >> 6;
        const int col = pos & 63;
        const float4 v = *(const float4*)(xb + ((size_t)row * WW + col) * CC + c4);
        s.x += v.x; s.y += v.y; s.z += v.z; s.w += v.w;
    }

    __shared__ float lds[16 * 64];
    lds[sub * 64 + c4 + 0] = s.x;
    lds[sub * 64 + c4 + 1] = s.y;
    lds[sub * 64 + c4 + 2] = s.z;
    lds[sub * 64 + c4 + 3] = s.w;
    __syncthreads();

    if (t < 64) {
        float acc = 0.f;
#pragma unroll
        for (int ss = 0; ss < 16; ++ss) acc += lds[ss * 64 + t];
        part[(((size_t)b * NTOK + n) * 16 + rc) * CC + t] = acc;
    }
}

// ---------------------------------------------------------------------------
// Stage 2: tokens -> qk -> dots -> softmax -> bf16 B-fragments (RNE).
// grid = HALF_B (one block per batch), batch-offset version.
// v9: phase-1 token reduce now uses float4 loads (thread = (n, c-quad),
// 16 float4 at 256-B stride; was scalar loads at 1-KB stride).
// ---------------------------------------------------------------------------
__global__ __launch_bounds__(256) void attn_kernel(const float* __restrict__ part,
                                                   const float* __restrict__ w_qkv, // [32][16]
                                                   unsigned short* __restrict__ fragw,
                                                   int b0) {
    const int b = b0 + blockIdx.x;
    const int t = threadIdx.x;

    __shared__ float tok[CC * NDIM];   // [c][n]
    __shared__ float ql [CC * NDIM];   // [c][n]
    __shared__ float kl [CC * NDIM];   // [c][n]
    __shared__ float dl [CC * CC];     // [i][j]
    __shared__ float rs [CC];          // 1/rowsum

    const float* pb = part + (size_t)b * NTOK * 16 * CC;

    // tokens[c][n] = mean over patch = (sum of 16 rc-partials)/4096
    // thread t -> n = t>>4, c-quad cq = t&15; float4 loads, all 256 threads.
    {
        const int n  = t >> 4;
        const int cq = t & 15;
        float4 a = make_float4(0.f, 0.f, 0.f, 0.f);
#pragma unroll
        for (int rc = 0; rc < 16; ++rc) {
            const float4 v = *(const float4*)(pb + ((size_t)n * 16 + rc) * CC + cq * 4);
            a.x += v.x; a.y += v.y; a.z += v.z; a.w += v.w;
        }
        tok[(cq * 4 + 0) * NDIM + n] = a.x * (1.0f / 4096.0f);
        tok[(cq * 4 + 1) * NDIM + n] = a.y * (1.0f / 4096.0f);
        tok[(cq * 4 + 2) * NDIM + n] = a.z * (1.0f / 4096.0f);
        tok[(cq * 4 + 3) * NDIM + n] = a.w * (1.0f / 4096.0f);
    }
    __syncthreads();

    // qk[c][d] = sum_n tok[c][n] * w[d][n];  split into q (d<16) and k
    for (int idx = t; idx < CC * 32; idx += 256) {
        const int c = idx >> 5, d = idx & 31;
        float a = 0.f;
#pragma unroll
        for (int n = 0; n < NDIM; ++n) a += tok[c * NDIM + n] * w_qkv[d * NDIM + n];
        if (d < 16) ql[c * NDIM + d] = a;
        else        kl[c * NDIM + (d - 16)] = a;
    }
    __syncthreads();

    // dots[i][j] = 0.25 * sum_n q[i][n]*k[j][n]
    for (int idx = t; idx < CC * CC; idx += 256) {
        const int i = idx >> 6, j = idx & 63;
        float a = 0.f;
#pragma unroll
        for (int n = 0; n < NDIM; ++n) a += ql[i * NDIM + n] * kl[j * NDIM + n];
        dl[idx] = a * 0.25f;
    }
    __syncthreads();

    // row softmax (64 rows, one thread each — tiny)
    if (t < CC) {
        float m = -1e30f;
        for (int j = 0; j < CC; ++j) m = fmaxf(m, dl[t * CC + j]);
        float ssum = 0.f;
        for (int j = 0; j < CC; ++j) {
            const float e = expf(dl[t * CC + j] - m);
            dl[t * CC + j] = e;
            ssum += e;
        }
        rs[t] = 1.0f / ssum;
    }
    __syncthreads();

    // Emit attn[t][c] = dl[t][c]*rs[t] as single-bf16 MFMA B-fragments.
    for (int idx = t; idx < 512; idx += 256) {
        const int tt   = idx >> 3;          // 0..63
        const int oct  = idx & 7;           // c octet
        const int ks   = oct >> 2;          // kstep = c>>5
        const int g    = oct & 3;           // lane>>4 group
        const int slot = (tt >> 4) * 2 + ks;         // 0..7
        const int lanei = (tt & 15) + g * 16;
        const float rr = rs[tt];
        s16x8 hi;
#pragma unroll
        for (int j = 0; j < 8; ++j)
            hi[j] = (short)f2bf_rne(dl[tt * CC + oct * 8 + j] * rr);
        s16x8* dst = (s16x8*)fragw + ((size_t)b * 8 + slot) * 64;
        dst[lanei] = hi;
    }
}

// ---------------------------------------------------------------------------
// Stage 3 (v9 = v8 body + batch offset): single-bf16 MFMA GEMM, B-in-VGPR,
// depth-2 x pipeline. out[p][t] = gelu(sum_c x[p][c]*attn[t][c])
// r5-r7 ablations: stage is pinned ~2x over its traffic floor by HBM miss
// LATENCY on the x re-read (issue count, barriers, pipeline depth all null).
// v9 attacks the misses themselves: kernel_launch pipelines per-half
// (pool->attn->out on 8 batches = 128 MiB working set in the 256-MiB L3,
// ~80% resident vs ~50% when all 256 MiB streams before out). Kernel body
// unchanged from v8 (passing, parity).
// A-frag: lane l -> row l&15, k (l>>4)*8+j; C/D: col=lane&15,
// row=(lane>>4)*4+reg (m89/m92-verified, r4-r7 passing).
// ---------------------------------------------------------------------------
__device__ __forceinline__ float gelu_fast(float v) {
    // gelu ~= v * sigmoid(1.59576912v + 0.07135482v^3); |err|<2e-4 for |v|<~1.
    const float u = v * v;
    const float z = v * fmaf(0.07135482f, u, 1.59576912f);
    const float e = exp2f(z * -1.44269504f);            // e^{-z}
    return v * __builtin_amdgcn_rcpf(e + 1.0f);
}

// pack 8 fp32 -> 8 bf16 (RNE) via v_cvt_pk_bf16_f32 (1 instr per 2 elems)
__device__ __forceinline__ s16x8 pack8(const float4 a, const float4 b) {
    union { unsigned int u[4]; s16x8 v; } r;
    asm("v_cvt_pk_bf16_f32 %0, %1, %2" : "=v"(r.u[0]) : "v"(a.x), "v"(a.y));
    asm("v_cvt_pk_bf16_f32 %0, %1, %2" : "=v"(r.u[1]) : "v"(a.z), "v"(a.w));
    asm("v_cvt_pk_bf16_f32 %0, %1, %2" : "=v"(r.u[2]) : "v"(b.x), "v"(b.y));
    asm("v_cvt_pk_bf16_f32 %0, %1, %2" : "=v"(r.u[3]) : "v"(b.z), "v"(b.w));
    return r.v;
}

__global__ __launch_bounds__(256) void out_mfma(const float* __restrict__ x,
                                                const unsigned short* __restrict__ frag,
                                                float* __restrict__ out,
                                                int b0) {
    const int tid  = threadIdx.x;
    const int lane = tid & 63;
    const int wv   = tid >> 6;
    const int blk  = b0 * 256 + (int)blockIdx.x;   // global block, 256 pixels each
    const int b    = blk >> 8;                     // 256 blocks per batch
    const int row  = lane & 15;
    const int g    = lane >> 4;

    const size_t pix0 = (size_t)blk * 256 + wv * 64;
    const float* xb = x + (pix0 + row) * CC + g * 8;

    // ---- issue x rowblock 0 ----
    float4 a0 = *(const float4*)(xb);
    float4 a1 = *(const float4*)(xb + 4);
    float4 a2 = *(const float4*)(xb + 32);
    float4 a3 = *(const float4*)(xb + 36);

    // ---- issue the 8 per-lane B-fragments (L2-hot, 16 B each) ----
    const s16x8* fb = (const s16x8*)(frag + (size_t)b * FRAG_USHORT_PER_B);
    s16x8 bf[8];
#pragma unroll
    for (int s = 0; s < 8; ++s) bf[s] = fb[s * 64 + lane];

    // ---- issue x rowblock 1 ----
    const float* x1 = xb + 16 * CC;
    float4 b0v = *(const float4*)(x1);
    float4 b1v = *(const float4*)(x1 + 4);
    float4 b2v = *(const float4*)(x1 + 32);
    float4 b3v = *(const float4*)(x1 + 36);

    float* ob = out + (pix0 + (g << 2)) * CC + row;   // row = lane&15 = t-in-tile

#define TCOLS(RB, AH0, AH1)                                                     \
    _Pragma("unroll")                                                           \
    for (int tcol = 0; tcol < 4; ++tcol) {                                      \
        f32x4 acc = {0.f, 0.f, 0.f, 0.f};                                       \
        acc = __builtin_amdgcn_mfma_f32_16x16x32_bf16(AH0, bf[tcol * 2], acc, 0, 0, 0);     \
        acc = __builtin_amdgcn_mfma_f32_16x16x32_bf16(AH1, bf[tcol * 2 + 1], acc, 0, 0, 0); \
        float* o = ob + (size_t)(RB) * 16 * CC + tcol * 16;                     \
        _Pragma("unroll")                                                       \
        for (int r = 0; r < 4; ++r) o[(size_t)r * CC] = gelu_fast(acc[r]);      \
    }

    // rb0: compute from A-buf, prefetch rb2 into A-buf
    {
        const s16x8 ah0 = pack8(a0, a1);
        const s16x8 ah1 = pack8(a2, a3);
        const float* nx = xb + 32 * CC;
        a0 = *(const float4*)(nx);
        a1 = *(const float4*)(nx + 4);
        a2 = *(const float4*)(nx + 32);
        a3 = *(const float4*)(nx + 36);
        TCOLS(0, ah0, ah1)
    }
    // rb1: compute from B-buf, prefetch rb3 into B-buf
    {
        const s16x8 ah0 = pack8(b0v, b1v);
        const s16x8 ah1 = pack8(b2v, b3v);
        const float* nx = xb + 48 * CC;
        b0v = *(const float4*)(nx);
        b1v = *(const float4*)(nx + 4);
        b2v = *(const float4*)(nx + 32);
        b3v = *(const float4*)(nx + 36);
        TCOLS(1, ah0, ah1)
    }
    // rb2: compute from A-buf
    {
        const s16x8 ah0 = pack8(a0, a1);
        const s16x8 ah1 = pack8(a2, a3);
        TCOLS(2, ah0, ah1)
    }
    // rb3: compute from B-buf
    {
        const s16x8 ah0 = pack8(b0v, b1v);
        const s16x8 ah1 = pack8(b2v, b3v);
        TCOLS(3, ah0, ah1)
    }
#undef TCOLS
}

// ---------------------------------------------------------------------------
// v9 launch: per-half pipelining. pool(8 batches) streams 128 MiB into the
// 256-MiB L3 (~80% resident, vs ~50% when all 256 MiB streams first), so
// out's x re-read becomes mostly L3 hits — attacking the measured latency
// wall (r5-r7: out pinned at ~2x traffic floor, invariant to issue count /
// barriers / pipeline depth / traversal order).
// ---------------------------------------------------------------------------
extern "C" void kernel_launch(void* const* d_in, const int* in_sizes, int n_in,
                              void* d_out, int out_size, void* d_ws, size_t ws_size,
                              hipStream_t stream) {
    const float* x     = (const float*)d_in[0];   // (16,256,256,64) fp32
    const float* w_qkv = (const float*)d_in[1];   // (32,16) fp32
    float* out   = (float*)d_out;                 // (16,256,256,64) fp32
    float* part  = (float*)d_ws;                  // 1 MiB
    unsigned short* frag = (unsigned short*)(part + PART_FLOATS); // 128 KiB

    for (int h = 0; h < 2; ++h) {
        const int b0 = h * HALF_B;
        pool_partial<<<HALF_B * NTOK * 16, 256, 0, stream>>>(x, part, b0);
        attn_kernel<<<HALF_B, 256, 0, stream>>>(part, w_qkv, frag, b0);
        out_mfma<<<HALF_B * 256, 256, 0, stream>>>(x, frag, out, b0);
    }
}